// Round 3
// baseline (14543.159 us; speedup 1.0000x reference)
//
#include <hip/hip_runtime.h>
#include <hip/hip_bf16.h>

// LSTM: B=512, T=256, H=1024, 2 layers + linear head.
// Per step t (kernel k): blocks 0-255 do layer0(t=k), blocks 256-511 do layer1(t=k-1).
// h0/h1 ping-pong buffered. GEMMs via split-precision f16 MFMA:
//   W = hi/512 (stored x512) + lo/2^20 (stored x2^20)   [scaling keeps lo f16-NORMAL:
//   unscaled w_lo ~ 7.6e-6 is denormal and was flushed -> round-1-level error]
//   h = hi + lo/2048 (lo stored x2048)
// accH accumulates ah*bh' (scale 2^9); accL accumulates ah*bl' + al'*bh' (scale 2^20).
// gate = accH/2^9 + accL/2^20 + bias. fp32 accumulate; cell update in-register.

#define B_   512
#define T_   256
#define H_   1024
#define BM   128
#define BH   16      // hidden cols per wg
#define BNG  64      // gate cols per wg = 4*BH
#define BK   64
#define PAD  8
#define LDK  (BK + PAD)   // 72 f16 = 144B row stride: 16B aligned, 2-way banks (free)
#define WSZ  4194304L     // 4096*1024
#define HBSZ 524288L      // 512*1024

#define WHI_SCALE   512.0f        // 2^9
#define WLO_SCALE   1048576.0f    // 2^20
#define HLO_SCALE   2048.0f       // 2^11
#define ACCH_DESC   (1.0f / 512.0f)
#define ACCL_DESC   (1.0f / 1048576.0f)

typedef _Float16 f16;
typedef _Float16 half8 __attribute__((ext_vector_type(8)));
typedef float f32x4 __attribute__((ext_vector_type(4)));

__device__ __forceinline__ float sigmoidf_fast(float x) {
  return 1.0f / (1.0f + __builtin_exp2f(-1.44269504f * x));   // x->-inf: 1/inf=0, no NaN
}
__device__ __forceinline__ float tanhf_fast(float x) {
  float ax = __builtin_fabsf(x);
  float e = __builtin_exp2f(-2.88539008f * ax);   // exp(-2|x|) <= 1, overflow-free
  float t = (1.0f - e) / (1.0f + e);
  return __builtin_copysignf(t, x);
}

__global__ void prep_kernel(const float* __restrict__ Whh0, const float* __restrict__ Wih1,
                            const float* __restrict__ Whh1,
                            const float* __restrict__ bih0, const float* __restrict__ bhh0,
                            const float* __restrict__ bih1, const float* __restrict__ bhh1,
                            const float* __restrict__ bl,
                            f16* __restrict__ Whh0h, f16* __restrict__ Wih1h, f16* __restrict__ Whh1h,
                            float* __restrict__ b0s, float* __restrict__ b1s,
                            f16* __restrict__ h0a, f16* __restrict__ h1a,
                            float* __restrict__ c0, float* __restrict__ c1,
                            float* __restrict__ y)
{
  const long W = WSZ, HB = HBSZ;
  const long total = 3 * W + 8192 + 4 * HB + 2 * HB + 131072;
  long idx = (long)blockIdx.x * 256 + threadIdx.x;
  long stride = (long)gridDim.x * 256;
  for (long i = idx; i < total; i += stride) {
    long r = i;
    if (r < 3 * W) {
      const float* src; f16* dst;
      if (r < W)          { src = Whh0; dst = Whh0h; }
      else if (r < 2 * W) { src = Wih1; dst = Wih1h; r -= W; }
      else                { src = Whh1; dst = Whh1h; r -= 2 * W; }
      float w = src[r];
      f16 hi = (f16)w;
      float hif = (float)hi;
      dst[r]     = (f16)(hif * WHI_SCALE);            // exact exponent shift
      dst[W + r] = (f16)((w - hif) * WLO_SCALE);      // residual, scaled to normal range
      continue;
    }
    r -= 3 * W;
    if (r < 4096) { b0s[r] = bih0[r] + bhh0[r]; continue; } r -= 4096;
    if (r < 4096) { b1s[r] = bih1[r] + bhh1[r]; continue; } r -= 4096;
    if (r < 2 * HB) { h0a[r] = (f16)0.0f; continue; } r -= 2 * HB;
    if (r < 2 * HB) { h1a[r] = (f16)0.0f; continue; } r -= 2 * HB;
    if (r < HB) { c0[r] = 0.0f; continue; } r -= HB;
    if (r < HB) { c1[r] = 0.0f; continue; } r -= HB;
    y[r] = bl[0];
  }
}

__launch_bounds__(256, 2)
__global__ void step_kernel(int t,
    const float* __restrict__ x,        // [512][256][2]
    const float* __restrict__ Wih0,     // [4096][2]
    const float* __restrict__ Wl,       // [1024]
    const f16* __restrict__ Whh0h,      // [2][4096][1024] hi*512 | lo*2^20
    const f16* __restrict__ Wih1h,
    const f16* __restrict__ Whh1h,
    const float* __restrict__ b0s, const float* __restrict__ b1s,
    f16* __restrict__ h0a, f16* __restrict__ h0b,   // [2][512][1024] hi | lo*2048
    f16* __restrict__ h1a, f16* __restrict__ h1b,
    float* __restrict__ c0, float* __restrict__ c1,
    float* __restrict__ y)              // [512][256]
{
  __shared__ f16 At[2][BM][LDK];   // [hi|lo]
  __shared__ f16 Bt[2][BNG][LDK];

  const int bid = blockIdx.x;
  const int tid = threadIdx.x;
  const bool l1 = bid >= 256;
  const int lb = bid & 255;
  const int mt = lb >> 6;         // 0..3 (M tile)
  const int hs = lb & 63;         // 0..63 (hidden slice)
  const int r0 = mt * BM;
  const int j0 = hs * BH;

  const f16 *hA, *hB = nullptr;
  const f16 *WA, *WB = nullptr;
  f16* hout; float* cc;
  int tt, NK;
  if (!l1) {
    if (t >= T_) return;
    tt = t;
    hA   = (t & 1) ? h0b : h0a;       // h0(t)
    hout = (t & 1) ? h0a : h0b;       // h0(t+1) slot
    WA = Whh0h;
    cc = c0; NK = H_ / BK;            // 16
  } else {
    if (t == 0) return;
    tt = t - 1;
    hA   = ((tt + 1) & 1) ? h0b : h0a;  // h0(tt) — written last kernel
    hB   = (tt & 1) ? h1b : h1a;        // h1(tt-1)
    hout = ((tt + 1) & 1) ? h1b : h1a;  // h1(tt)
    WA = Wih1h; WB = Whh1h;
    cc = c1; NK = 2 * H_ / BK;          // 32
  }

  const int lane = tid & 63;
  const int wv = tid >> 6;
  const int sr = tid >> 3;   // 0..31 staging row base
  const int sc = tid & 7;    // 0..7 staging 16B chunk

  f32x4 accH[2][4] = {};
  f32x4 accL[2][4] = {};
  f32x4 ar[8];   // A: hi[0..3], lo[4..7]
  f32x4 br[4];   // B: hi[0..1], lo[2..3]

  auto stage_load = [&](int ki) {
    const f16* hsrc; const f16* wsrc; int ko;
    if (!l1 || ki < 16) { hsrc = hA; wsrc = WA; ko = ki * BK; }
    else                { hsrc = hB; wsrc = WB; ko = (ki - 16) * BK; }
    #pragma unroll
    for (int i = 0; i < 4; i++) {
      int row = sr + 32 * i;
      long off = (long)(r0 + row) * H_ + ko + sc * 8;
      ar[i]     = *(const f32x4*)&hsrc[off];
      ar[4 + i] = *(const f32x4*)&hsrc[HBSZ + off];
    }
    #pragma unroll
    for (int i = 0; i < 2; i++) {
      int row = sr + 32 * i;                       // 0..63 gate-col within tile
      long off = (long)((row >> 4) * H_ + j0 + (row & 15)) * H_ + ko + sc * 8;
      br[i]     = *(const f32x4*)&wsrc[off];
      br[2 + i] = *(const f32x4*)&wsrc[WSZ + off];
    }
  };
  auto stage_store = [&]() {
    #pragma unroll
    for (int i = 0; i < 4; i++) {
      int row = sr + 32 * i;
      *(f32x4*)&At[0][row][sc * 8] = ar[i];
      *(f32x4*)&At[1][row][sc * 8] = ar[4 + i];
    }
    #pragma unroll
    for (int i = 0; i < 2; i++) {
      int row = sr + 32 * i;
      *(f32x4*)&Bt[0][row][sc * 8] = br[i];
      *(f32x4*)&Bt[1][row][sc * 8] = br[2 + i];
    }
  };
  auto do_compute = [&]() {
    const int arow = wv * 32 + (lane & 15);
    const int bcol = lane & 15;
    const int kq = (lane >> 4) * 8;
    #pragma unroll
    for (int kk = 0; kk < 2; kk++) {
      half8 ah[2], al[2], bh[4], bl_[4];
      #pragma unroll
      for (int mi = 0; mi < 2; mi++) {
        ah[mi] = *(const half8*)&At[0][arow + mi * 16][kk * 32 + kq];
        al[mi] = *(const half8*)&At[1][arow + mi * 16][kk * 32 + kq];
      }
      #pragma unroll
      for (int ni = 0; ni < 4; ni++) {
        bh[ni]  = *(const half8*)&Bt[0][ni * 16 + bcol][kk * 32 + kq];
        bl_[ni] = *(const half8*)&Bt[1][ni * 16 + bcol][kk * 32 + kq];
      }
      #pragma unroll
      for (int mi = 0; mi < 2; mi++)
        #pragma unroll
        for (int ni = 0; ni < 4; ni++) {
          accH[mi][ni] = __builtin_amdgcn_mfma_f32_16x16x32_f16(ah[mi], bh[ni],  accH[mi][ni], 0, 0, 0);
          accL[mi][ni] = __builtin_amdgcn_mfma_f32_16x16x32_f16(ah[mi], bl_[ni], accL[mi][ni], 0, 0, 0);
          accL[mi][ni] = __builtin_amdgcn_mfma_f32_16x16x32_f16(al[mi], bh[ni],  accL[mi][ni], 0, 0, 0);
        }
    }
  };

  // 1-deep pipelined K loop (stage ki stored, ki+1 loads overlap compute)
  stage_load(0);
  for (int ki = 0; ki < NK; ki++) {
    __syncthreads();
    stage_store();
    __syncthreads();
    if (ki + 1 < NK) stage_load(ki + 1);
    do_compute();
  }

  // ---------------- epilogue: LSTM cell, fully in-register ----------------
  const int j = j0 + (lane & 15);
  const float* bs = l1 ? b1s : b0s;
  float bsum[4], wi0[4][2];
  #pragma unroll
  for (int g = 0; g < 4; g++) bsum[g] = bs[g * H_ + j];
  if (!l1) {
    #pragma unroll
    for (int g = 0; g < 4; g++) {
      wi0[g][0] = Wih0[(g * H_ + j) * 2 + 0];
      wi0[g][1] = Wih0[(g * H_ + j) * 2 + 1];
    }
  }
  const float wl = l1 ? Wl[j] : 0.0f;

  #pragma unroll
  for (int mi = 0; mi < 2; mi++) {
    #pragma unroll
    for (int r = 0; r < 4; r++) {
      int row = r0 + wv * 32 + mi * 16 + ((lane >> 4) & 3) * 4 + r;
      float gi = accH[mi][0][r] * ACCH_DESC + accL[mi][0][r] * ACCL_DESC + bsum[0];
      float gf = accH[mi][1][r] * ACCH_DESC + accL[mi][1][r] * ACCL_DESC + bsum[1];
      float gg = accH[mi][2][r] * ACCH_DESC + accL[mi][2][r] * ACCL_DESC + bsum[2];
      float go = accH[mi][3][r] * ACCH_DESC + accL[mi][3][r] * ACCL_DESC + bsum[3];
      if (!l1) {
        float x0 = x[(row * T_ + tt) * 2 + 0];
        float x1 = x[(row * T_ + tt) * 2 + 1];
        gi += x0 * wi0[0][0] + x1 * wi0[0][1];
        gf += x0 * wi0[1][0] + x1 * wi0[1][1];
        gg += x0 * wi0[2][0] + x1 * wi0[2][1];
        go += x0 * wi0[3][0] + x1 * wi0[3][1];
      }
      float ig = sigmoidf_fast(gi);
      float fg = sigmoidf_fast(gf);
      float gv = tanhf_fast(gg);
      float ov = sigmoidf_fast(go);
      int cidx = row * H_ + j;
      float cn = fg * cc[cidx] + ig * gv;
      cc[cidx] = cn;
      float hn = ov * tanhf_fast(cn);
      f16 hhi = (f16)hn;
      hout[cidx] = hhi;
      hout[cidx + HBSZ] = (f16)((hn - (float)hhi) * HLO_SCALE);
      if (l1) {
        float yp = hn * wl;
        #pragma unroll
        for (int s = 1; s < 16; s <<= 1) yp += __shfl_xor(yp, s, 64);
        if ((lane & 15) == 0) atomicAdd(&y[row * T_ + tt], yp);
      }
    }
  }
}

extern "C" void kernel_launch(void* const* d_in, const int* in_sizes, int n_in,
                              void* d_out, int out_size, void* d_ws, size_t ws_size,
                              hipStream_t stream) {
  (void)in_sizes; (void)n_in; (void)out_size; (void)ws_size;
  const float* x    = (const float*)d_in[0];
  const float* Wih0 = (const float*)d_in[1];
  const float* Whh0 = (const float*)d_in[2];
  const float* bih0 = (const float*)d_in[3];
  const float* bhh0 = (const float*)d_in[4];
  const float* Wih1 = (const float*)d_in[5];
  const float* Whh1 = (const float*)d_in[6];
  const float* bih1 = (const float*)d_in[7];
  const float* bhh1 = (const float*)d_in[8];
  const float* Wl   = (const float*)d_in[9];
  const float* bl   = (const float*)d_in[10];
  float* y = (float*)d_out;

  char* ws = (char*)d_ws;
  size_t off = 0;
  auto alloc = [&](size_t bytes) { char* p = ws + off; off += (bytes + 255) & ~255UL; return p; };
  f16*   Whh0h = (f16*)alloc(2 * WSZ * sizeof(f16));   // hi*512 | lo*2^20
  f16*   Wih1h = (f16*)alloc(2 * WSZ * sizeof(f16));
  f16*   Whh1h = (f16*)alloc(2 * WSZ * sizeof(f16));
  float* b0s   = (float*)alloc(4096 * sizeof(float));
  float* b1s   = (float*)alloc(4096 * sizeof(float));
  f16*   h0a   = (f16*)alloc(2 * HBSZ * sizeof(f16));  // hi | lo*2048
  f16*   h0b   = (f16*)alloc(2 * HBSZ * sizeof(f16));
  f16*   h1a   = (f16*)alloc(2 * HBSZ * sizeof(f16));
  f16*   h1b   = (f16*)alloc(2 * HBSZ * sizeof(f16));
  float* c0    = (float*)alloc(HBSZ * sizeof(float));
  float* c1    = (float*)alloc(HBSZ * sizeof(float));
  // total ~63 MB of d_ws

  hipLaunchKernelGGL(prep_kernel, dim3(2048), dim3(256), 0, stream,
      Whh0, Wih1, Whh1, bih0, bhh0, bih1, bhh1, bl,
      Whh0h, Wih1h, Whh1h, b0s, b1s, h0a, h1a, c0, c1, y);

  for (int t = 0; t <= T_; t++) {
    hipLaunchKernelGGL(step_kernel, dim3(512), dim3(256), 0, stream, t,
        x, Wih0, Wl, Whh0h, Wih1h, Whh1h, b0s, b1s,
        h0a, h0b, h1a, h1b, c0, c1, y);
  }
}